// Round 1
// baseline (108.191 us; speedup 1.0000x reference)
//
#include <hip/hip_runtime.h>

#define BATCH 32768
#define FEAT 512
#define KCENT 2

// One wave (64 lanes) per sample. 4 samples per 256-thread block.
__global__ __launch_bounds__(256) void mcl_partial(
    const float* __restrict__ x,
    const int* __restrict__ labels,
    const float* __restrict__ centers,
    float* __restrict__ partial)
{
    const int wave = threadIdx.x >> 6;
    const int lane = threadIdx.x & 63;
    const int sample = blockIdx.x * 4 + wave;

    const int lab = labels[sample];
    const float* __restrict__ xrow = x + (size_t)sample * FEAT;
    const float* __restrict__ c0 = centers + (size_t)lab * (KCENT * FEAT);
    const float* __restrict__ c1 = c0 + FEAT;

    float d0 = 0.f, d1 = 0.f;
#pragma unroll
    for (int j = 0; j < 2; ++j) {
        const int off = j * 256 + lane * 4;   // 16B per lane, coalesced
        const float4 xv = *(const float4*)(xrow + off);
        const float4 a  = *(const float4*)(c0 + off);
        const float4 b  = *(const float4*)(c1 + off);
        float e;
        e = xv.x - a.x; d0 += e * e;
        e = xv.y - a.y; d0 += e * e;
        e = xv.z - a.z; d0 += e * e;
        e = xv.w - a.w; d0 += e * e;
        e = xv.x - b.x; d1 += e * e;
        e = xv.y - b.y; d1 += e * e;
        e = xv.z - b.z; d1 += e * e;
        e = xv.w - b.w; d1 += e * e;
    }

    // wave-64 reduction of both distances
#pragma unroll
    for (int s = 32; s > 0; s >>= 1) {
        d0 += __shfl_down(d0, s, 64);
        d1 += __shfl_down(d1, s, 64);
    }

    __shared__ float smin[4];
    if (lane == 0) smin[wave] = fminf(d0, d1);
    __syncthreads();
    if (threadIdx.x == 0)
        partial[blockIdx.x] = (smin[0] + smin[1]) + (smin[2] + smin[3]);
}

__global__ __launch_bounds__(256) void mcl_final(
    const float* __restrict__ partial, int n, float* __restrict__ out)
{
    float s = 0.f;
    for (int i = threadIdx.x; i < n; i += 256) s += partial[i];
#pragma unroll
    for (int sh = 32; sh > 0; sh >>= 1) s += __shfl_down(s, sh, 64);
    __shared__ float ws[4];
    const int wave = threadIdx.x >> 6;
    const int lane = threadIdx.x & 63;
    if (lane == 0) ws[wave] = s;
    __syncthreads();
    if (threadIdx.x == 0)
        out[0] = ((ws[0] + ws[1]) + (ws[2] + ws[3])) * (1.0f / (float)BATCH);
}

extern "C" void kernel_launch(void* const* d_in, const int* in_sizes, int n_in,
                              void* d_out, int out_size, void* d_ws, size_t ws_size,
                              hipStream_t stream) {
    const float* x       = (const float*)d_in[0];
    const int*   labels  = (const int*)d_in[1];
    const float* centers = (const float*)d_in[2];
    float* out = (float*)d_out;
    float* partial = (float*)d_ws;

    const int nblocks = BATCH / 4;  // 8192 blocks, 1 sample per wave
    mcl_partial<<<nblocks, 256, 0, stream>>>(x, labels, centers, partial);
    mcl_final<<<1, 256, 0, stream>>>(partial, nblocks, out);
}